// Round 7
// baseline (234.254 us; speedup 1.0000x reference)
//
#include <hip/hip_runtime.h>

#define BATCH 2
#define L_SEQ 2048
#define DI 2048
#define NROW (BATCH * L_SEQ)   // 4096
#define E_DIM 96
#define RNK 64                 // DT_RANK
#define NST 16                 // D_STATE
#define NCH 64                 // chunks
#define CL 32                  // chunk length (NCH*CL == L_SEQ)
#define SPLITK 16              // K1 split-K factor
#define KSL (DI / SPLITK)      // 128 k per split

// ---------------- workspace layout (floats) ----------------
// xdbl  : [NROW][96]                              393216
// region2 (overlaid, disjoint lifetimes):
//   partials : [SPLITK][NROW][96]   6291456  (K1 -> reduce, then dead)
//   hloc     : [BATCH][NCH][DI][16] 4194304  (S1 -> S3)
//   dsum     : [BATCH][NCH][DI]      262144
#define WS_XDBL 0
#define WS_PART 393216
#define WS_HLOC 393216
#define WS_DSUM (393216 + 4194304)

__device__ __forceinline__ float softplusf(float z) {
    return fmaxf(z, 0.f) + __logf(1.f + __expf(-fabsf(z)));
}

// ===== K1a: partial[s] = x[:, ksl] @ W^T slice =====
__global__ __launch_bounds__(256) void gemm_xproj_part(const float* __restrict__ x,
                                                       const float* __restrict__ Wx,
                                                       float* __restrict__ part) {
    __shared__ float xs[32][68];    // [k][row], pitch 272B (16B aligned)
    __shared__ float wsh[32][100];  // [k][e],  pitch 400B (16B aligned)
    const int tid = threadIdx.x;
    const int r0 = blockIdx.x * 64;
    const int kbase0 = blockIdx.y * KSL;
    const int rg = tid >> 4;   // 16 groups of 4 rows
    const int cg = tid & 15;   // 16 groups of 6 cols

    float acc[4][6];
#pragma unroll
    for (int i = 0; i < 4; i++)
#pragma unroll
        for (int j = 0; j < 6; j++) acc[i][j] = 0.f;

    for (int kt = 0; kt < KSL / 32; kt++) {
        const int kb = kbase0 + kt * 32;
#pragma unroll
        for (int rep = 0; rep < 2; rep++) {
            int i = rep * 256 + tid;   // 0..511
            int row = i >> 3;          // 0..63
            int kq = i & 7;
            float4 v = *(const float4*)&x[(long)(r0 + row) * DI + kb + kq * 4];
            xs[kq * 4 + 0][row] = v.x;
            xs[kq * 4 + 1][row] = v.y;
            xs[kq * 4 + 2][row] = v.z;
            xs[kq * 4 + 3][row] = v.w;
        }
#pragma unroll
        for (int rep = 0; rep < 3; rep++) {
            int i = rep * 256 + tid;   // 0..767
            int e = i >> 3;            // 0..95
            int kq = i & 7;
            float4 v = *(const float4*)&Wx[(long)e * DI + kb + kq * 4];
            wsh[kq * 4 + 0][e] = v.x;
            wsh[kq * 4 + 1][e] = v.y;
            wsh[kq * 4 + 2][e] = v.z;
            wsh[kq * 4 + 3][e] = v.w;
        }
        __syncthreads();
#pragma unroll 8
        for (int k = 0; k < 32; k++) {
            float xr[4], wr[6];
#pragma unroll
            for (int i = 0; i < 4; i++) xr[i] = xs[k][rg * 4 + i];
#pragma unroll
            for (int j = 0; j < 6; j++) wr[j] = wsh[k][cg * 6 + j];
#pragma unroll
            for (int i = 0; i < 4; i++)
#pragma unroll
                for (int j = 0; j < 6; j++) acc[i][j] = fmaf(xr[i], wr[j], acc[i][j]);
        }
        __syncthreads();
    }
    const long sbase = (long)blockIdx.y * NROW * E_DIM;
#pragma unroll
    for (int i = 0; i < 4; i++) {
        long rowb = sbase + (long)(r0 + rg * 4 + i) * E_DIM + cg * 6;
#pragma unroll
        for (int j = 0; j < 6; j++) part[rowb + j] = acc[i][j];
    }
}

// ===== K1b: xdbl = sum over splits (float4-vectorized) =====
__global__ __launch_bounds__(256) void xproj_reduce(const float* __restrict__ part,
                                                    float* __restrict__ xdbl) {
    const int i4 = blockIdx.x * 256 + threadIdx.x;   // 98304 float4 outputs
    const float4* p4 = (const float4*)part;
    float4 s = p4[i4];
#pragma unroll
    for (int sp = 1; sp < SPLITK; sp++) {
        float4 v = p4[(long)sp * (NROW * E_DIM / 4) + i4];
        s.x += v.x; s.y += v.y; s.z += v.z; s.w += v.w;
    }
    ((float4*)xdbl)[i4] = s;
}

// ===== S1 (delta recomputed inline): chunk-local carries =====
// dlt rows staged in LDS (broadcast); Wdt[d] read in 16-reg quarters;
// 32 independent ddot accumulators (no serial chain). delta never hits HBM.
__global__ __launch_bounds__(256, 4) void scan_carry_dt(const float* __restrict__ x,
                                                        const float* __restrict__ xdbl,
                                                        const float* __restrict__ Wdt,
                                                        const float* __restrict__ bdt,
                                                        const float* __restrict__ A_log,
                                                        float* __restrict__ hloc,
                                                        float* __restrict__ dsumb) {
    __shared__ float dlt_s[CL][RNK];   // 8 KB
    __shared__ float bs[CL * NST];     // 2 KB
    const int tid = threadIdx.x;
    const int d = blockIdx.x * 256 + tid;
    const int c = blockIdx.y;
    const int b = blockIdx.z;
    const int row0 = b * L_SEQ + c * CL;

    for (int i = tid; i < CL * 16; i += 256) {   // 512 float4
        int row = i >> 4, q = i & 15;
        *(float4*)&dlt_s[row][q * 4] =
            *(const float4*)&xdbl[(long)(row0 + row) * E_DIM + q * 4];
    }
    for (int i = tid; i < CL * 4; i += 256) {    // 128 float4
        int row = i >> 2, q = i & 3;
        ((float4*)bs)[i] = *(const float4*)&xdbl[(long)(row0 + row) * E_DIM + 64 + q * 4];
    }
    __syncthreads();

    // ddot[l] = dot(dlt[l][:], Wdt[d][:]) — quarters of K keep W regs at 16
    float ddot[CL];
#pragma unroll
    for (int l = 0; l < CL; l++) ddot[l] = 0.f;
#pragma unroll
    for (int kq = 0; kq < 4; kq++) {
        const float* wp = &Wdt[(long)d * RNK + kq * 16];
        float4 w0 = *(const float4*)&wp[0];
        float4 w1 = *(const float4*)&wp[4];
        float4 w2 = *(const float4*)&wp[8];
        float4 w3 = *(const float4*)&wp[12];
#pragma unroll
        for (int l = 0; l < CL; l++) {
            float4 s0 = *(const float4*)&dlt_s[l][kq * 16 + 0];
            float4 s1 = *(const float4*)&dlt_s[l][kq * 16 + 4];
            float4 s2 = *(const float4*)&dlt_s[l][kq * 16 + 8];
            float4 s3 = *(const float4*)&dlt_s[l][kq * 16 + 12];
            float t = ddot[l];
            t = fmaf(s0.x, w0.x, t); t = fmaf(s0.y, w0.y, t);
            t = fmaf(s0.z, w0.z, t); t = fmaf(s0.w, w0.w, t);
            t = fmaf(s1.x, w1.x, t); t = fmaf(s1.y, w1.y, t);
            t = fmaf(s1.z, w1.z, t); t = fmaf(s1.w, w1.w, t);
            t = fmaf(s2.x, w2.x, t); t = fmaf(s2.y, w2.y, t);
            t = fmaf(s2.z, w2.z, t); t = fmaf(s2.w, w2.w, t);
            t = fmaf(s3.x, w3.x, t); t = fmaf(s3.y, w3.y, t);
            t = fmaf(s3.z, w3.z, t); t = fmaf(s3.w, w3.w, t);
            ddot[l] = t;
        }
    }
    const float bd = bdt[d];

    float A[16];
#pragma unroll
    for (int q = 0; q < 4; q++) {
        float4 v = *(const float4*)&A_log[(long)d * NST + q * 4];
        A[q * 4 + 0] = -__expf(v.x);
        A[q * 4 + 1] = -__expf(v.y);
        A[q * 4 + 2] = -__expf(v.z);
        A[q * 4 + 3] = -__expf(v.w);
    }
    float h[16];
#pragma unroll
    for (int n = 0; n < 16; n++) h[n] = 0.f;
    float dsum = 0.f;

    long idx = (long)row0 * DI + d;
    float xn = x[idx];
#pragma unroll 4
    for (int ll = 0; ll < CL; ll++) {
        float xc = xn;
        if (ll + 1 < CL) xn = x[idx + DI];
        float dc = softplusf(ddot[ll] + bd);
        float du = dc * xc;
#pragma unroll
        for (int q = 0; q < 4; q++) {
            float4 v = *(const float4*)&bs[ll * NST + q * 4];   // broadcast
            h[q * 4 + 0] = fmaf(__expf(dc * A[q * 4 + 0]), h[q * 4 + 0], du * v.x);
            h[q * 4 + 1] = fmaf(__expf(dc * A[q * 4 + 1]), h[q * 4 + 1], du * v.y);
            h[q * 4 + 2] = fmaf(__expf(dc * A[q * 4 + 2]), h[q * 4 + 2], du * v.z);
            h[q * 4 + 3] = fmaf(__expf(dc * A[q * 4 + 3]), h[q * 4 + 3], du * v.w);
        }
        dsum += dc;
        idx += DI;
    }

    const long cb = ((long)(b * NCH + c) * DI + d);
#pragma unroll
    for (int q = 0; q < 4; q++)
        *(float4*)&hloc[cb * 16 + q * 4] =
            make_float4(h[q * 4], h[q * 4 + 1], h[q * 4 + 2], h[q * 4 + 3]);
    dsumb[cb] = dsum;
}

// ===== S2: prefix over chunks; hloc becomes chunk-entry state =====
__global__ __launch_bounds__(256) void scan_prefix(const float* __restrict__ A_log,
                                                   float* __restrict__ hloc,
                                                   const float* __restrict__ dsumb) {
    const int g = blockIdx.x * 256 + threadIdx.x;   // 65536 threads
    const int n = g & 15;
    const int d = (g >> 4) & (DI - 1);
    const int b = g >> 15;
    const float An = -__expf(A_log[(long)d * NST + n]);
    float hc = 0.f;
    for (int c = 0; c < NCH; c++) {
        const long cb = ((long)(b * NCH + c) * DI + d);
        float hl = hloc[cb * 16 + n];
        float dsv = dsumb[cb];
        hloc[cb * 16 + n] = hc;               // overwrite with entry state
        hc = fmaf(__expf(An * dsv), hc, hl);  // state at end of chunk c
    }
}

// ===== S3 (delta recomputed inline): output pass from true h_init =====
__global__ __launch_bounds__(256, 4) void scan_out_dt(const float* __restrict__ x,
                                                      const float* __restrict__ xdbl,
                                                      const float* __restrict__ Wdt,
                                                      const float* __restrict__ bdt,
                                                      const float* __restrict__ A_log,
                                                      const float* __restrict__ Dp,
                                                      const float* __restrict__ hloc,
                                                      float* __restrict__ out) {
    __shared__ float dlt_s[CL][RNK];   // 8 KB
    __shared__ float bs[CL * NST];     // 2 KB
    __shared__ float cs[CL * NST];     // 2 KB
    const int tid = threadIdx.x;
    const int d = blockIdx.x * 256 + tid;
    const int c = blockIdx.y;
    const int b = blockIdx.z;
    const int row0 = b * L_SEQ + c * CL;

    for (int i = tid; i < CL * 16; i += 256) {
        int row = i >> 4, q = i & 15;
        *(float4*)&dlt_s[row][q * 4] =
            *(const float4*)&xdbl[(long)(row0 + row) * E_DIM + q * 4];
    }
    for (int i = tid; i < CL * 4; i += 256) {
        int row = i >> 2, q = i & 3;
        ((float4*)bs)[i] = *(const float4*)&xdbl[(long)(row0 + row) * E_DIM + 64 + q * 4];
        ((float4*)cs)[i] = *(const float4*)&xdbl[(long)(row0 + row) * E_DIM + 80 + q * 4];
    }
    __syncthreads();

    float ddot[CL];
#pragma unroll
    for (int l = 0; l < CL; l++) ddot[l] = 0.f;
#pragma unroll
    for (int kq = 0; kq < 4; kq++) {
        const float* wp = &Wdt[(long)d * RNK + kq * 16];
        float4 w0 = *(const float4*)&wp[0];
        float4 w1 = *(const float4*)&wp[4];
        float4 w2 = *(const float4*)&wp[8];
        float4 w3 = *(const float4*)&wp[12];
#pragma unroll
        for (int l = 0; l < CL; l++) {
            float4 s0 = *(const float4*)&dlt_s[l][kq * 16 + 0];
            float4 s1 = *(const float4*)&dlt_s[l][kq * 16 + 4];
            float4 s2 = *(const float4*)&dlt_s[l][kq * 16 + 8];
            float4 s3 = *(const float4*)&dlt_s[l][kq * 16 + 12];
            float t = ddot[l];
            t = fmaf(s0.x, w0.x, t); t = fmaf(s0.y, w0.y, t);
            t = fmaf(s0.z, w0.z, t); t = fmaf(s0.w, w0.w, t);
            t = fmaf(s1.x, w1.x, t); t = fmaf(s1.y, w1.y, t);
            t = fmaf(s1.z, w1.z, t); t = fmaf(s1.w, w1.w, t);
            t = fmaf(s2.x, w2.x, t); t = fmaf(s2.y, w2.y, t);
            t = fmaf(s2.z, w2.z, t); t = fmaf(s2.w, w2.w, t);
            t = fmaf(s3.x, w3.x, t); t = fmaf(s3.y, w3.y, t);
            t = fmaf(s3.z, w3.z, t); t = fmaf(s3.w, w3.w, t);
            ddot[l] = t;
        }
    }
    const float bd = bdt[d];

    float A[16];
#pragma unroll
    for (int q = 0; q < 4; q++) {
        float4 v = *(const float4*)&A_log[(long)d * NST + q * 4];
        A[q * 4 + 0] = -__expf(v.x);
        A[q * 4 + 1] = -__expf(v.y);
        A[q * 4 + 2] = -__expf(v.z);
        A[q * 4 + 3] = -__expf(v.w);
    }
    float h[16];
    const long cb = ((long)(b * NCH + c) * DI + d);
#pragma unroll
    for (int q = 0; q < 4; q++) {
        float4 v = *(const float4*)&hloc[cb * 16 + q * 4];
        h[q * 4 + 0] = v.x; h[q * 4 + 1] = v.y; h[q * 4 + 2] = v.z; h[q * 4 + 3] = v.w;
    }
    const float Dd = Dp[d];

    long idx = (long)row0 * DI + d;
    float xn = x[idx];
#pragma unroll 4
    for (int ll = 0; ll < CL; ll++) {
        float xc = xn;
        if (ll + 1 < CL) xn = x[idx + DI];
        float dc = softplusf(ddot[ll] + bd);
        float du = dc * xc;
        float y = 0.f;
#pragma unroll
        for (int q = 0; q < 4; q++) {
            float4 v = *(const float4*)&bs[ll * NST + q * 4];
            float4 w = *(const float4*)&cs[ll * NST + q * 4];
            h[q * 4 + 0] = fmaf(__expf(dc * A[q * 4 + 0]), h[q * 4 + 0], du * v.x);
            h[q * 4 + 1] = fmaf(__expf(dc * A[q * 4 + 1]), h[q * 4 + 1], du * v.y);
            h[q * 4 + 2] = fmaf(__expf(dc * A[q * 4 + 2]), h[q * 4 + 2], du * v.z);
            h[q * 4 + 3] = fmaf(__expf(dc * A[q * 4 + 3]), h[q * 4 + 3], du * v.w);
            y = fmaf(h[q * 4 + 0], w.x, y);
            y = fmaf(h[q * 4 + 1], w.y, y);
            y = fmaf(h[q * 4 + 2], w.z, y);
            y = fmaf(h[q * 4 + 3], w.w, y);
        }
        out[idx] = fmaf(xc, Dd, y);
        idx += DI;
    }
}

extern "C" void kernel_launch(void* const* d_in, const int* in_sizes, int n_in,
                              void* d_out, int out_size, void* d_ws, size_t ws_size,
                              hipStream_t stream) {
    const float* x    = (const float*)d_in[0];
    const float* Wx   = (const float*)d_in[1];
    const float* Wdt  = (const float*)d_in[2];
    const float* bdt  = (const float*)d_in[3];
    const float* Alog = (const float*)d_in[4];
    const float* Dp   = (const float*)d_in[5];
    float* out = (float*)d_out;
    float* ws = (float*)d_ws;
    float* xdbl  = ws + WS_XDBL;
    float* partb = ws + WS_PART;
    float* hloc  = ws + WS_HLOC;   // overlays partb (disjoint lifetime)
    float* dsumb = ws + WS_DSUM;

    gemm_xproj_part<<<dim3(NROW / 64, SPLITK), 256, 0, stream>>>(x, Wx, partb);
    xproj_reduce<<<dim3(NROW * E_DIM / 4 / 256), 256, 0, stream>>>(partb, xdbl);
    scan_carry_dt<<<dim3(DI / 256, NCH, BATCH), 256, 0, stream>>>(x, xdbl, Wdt, bdt,
                                                                  Alog, hloc, dsumb);
    scan_prefix<<<dim3(BATCH * DI * NST / 256), 256, 0, stream>>>(Alog, hloc, dsumb);
    scan_out_dt<<<dim3(DI / 256, NCH, BATCH), 256, 0, stream>>>(x, xdbl, Wdt, bdt,
                                                                Alog, Dp, hloc, out);
}